// Round 6
// baseline (813.723 us; speedup 1.0000x reference)
//
#include <hip/hip_runtime.h>

typedef _Float16 f16;
typedef f16 f16x8 __attribute__((ext_vector_type(8)));
typedef f16 f16x4 __attribute__((ext_vector_type(4)));
typedef float f32x4 __attribute__((ext_vector_type(4)));

#define BDIM 16
#define MDIM 4
#define NDIM 4096
#define NB   64
#define NTILES (NDIM/NB)          // 64
#define NBMT  (BDIM*MDIM*NTILES)  // 4096

#define MFMA16(a,b,c) __builtin_amdgcn_mfma_f32_16x16x32_f16(a, b, c, 0, 0, 0)

// ---------------- prep: fp32 weights -> f16 fragment layout ----------------
// W1s: [e][kb(64)][o(128)][ki(8)]   W2s: [e][kb(16)][o(48)][ki(8)]
// W3s: [e][kb(8)][o(16)][ki(8)] (K padded 48->64 with zeros)
__global__ __launch_bounds__(256) void prep_kernel(
    const float* __restrict__ W1, const float* __restrict__ W2, const float* __restrict__ W3,
    f16* __restrict__ W1s, f16* __restrict__ W2s, f16* __restrict__ W3s)
{
  int i = blockIdx.x * 256 + threadIdx.x;
  if (i < 262144) {
    int ki = i & 7; int rest = i >> 3;
    int o = rest & 127; rest >>= 7;
    int kb = rest & 63; int e = rest >> 6;
    W1s[i] = (f16)W1[(e*128 + o)*512 + kb*8 + ki];
  } else if (i < 262144 + 24576) {
    int j = i - 262144;
    int ki = j & 7; int rest = j >> 3;
    int o = rest % 48; rest /= 48;
    int kb = rest & 15; int e = rest >> 4;
    W2s[j] = (f16)W2[(e*48 + o)*128 + kb*8 + ki];
  } else if (i < 262144 + 24576 + 4096) {
    int j = i - 262144 - 24576;
    int ki = j & 7; int rest = j >> 3;
    int o = rest & 15; rest >>= 4;
    int kb = rest & 7; int e = rest >> 3;
    int k = kb*8 + ki;
    W3s[j] = (k < 48) ? (f16)W3[(e*16 + o)*48 + k] : (f16)0.f;
  }
}

// ---------------- xprep: coalesced read + register transpose --------------
// block = (bm, cb): 8 channels (c = cb*8+ci) x all 4096 n. 256 threads.
// Reads 8 x 16 KiB rows coalesced; writes Xt[bm][tile][cb][p][ci] f16 in
// 64 B/thread contiguous chunks. Also produces complete pooled sums.
__global__ __launch_bounds__(256) void xprep_kernel(
    const float* __restrict__ x, f16* __restrict__ Xt, float* __restrict__ partial)
{
  const int bid = blockIdx.x;            // bm*64 + cb
  const int cb  = bid & 63;
  const int bm  = bid >> 6;              // b*4 + m
  const int b   = bm >> 2, m = bm & 3;
  const int t   = threadIdx.x;
  const int lane = t & 63, wid = t >> 6;

  __shared__ float red[4][8];
  float s[8] = {0.f,0.f,0.f,0.f,0.f,0.f,0.f,0.f};

  #pragma unroll
  for (int pass = 0; pass < 4; ++pass) {
    const int n0 = pass*1024 + t*4;
    f32x4 v[8];
    #pragma unroll
    for (int ci = 0; ci < 8; ++ci)
      v[ci] = *(const f32x4*)(x + (((size_t)(b*512 + cb*8 + ci))*4 + m)*4096 + n0);
    #pragma unroll
    for (int ci = 0; ci < 8; ++ci)
      s[ci] += v[ci][0] + v[ci][1] + v[ci][2] + v[ci][3];
    const int tile = n0 >> 6, p = n0 & 63;
    const size_t obase = (((size_t)bm*64 + tile)*64 + cb)*64;
    #pragma unroll
    for (int i = 0; i < 4; ++i) {
      f16x8 o;
      #pragma unroll
      for (int ci = 0; ci < 8; ++ci) o[ci] = (f16)v[ci][i];
      *(f16x8*)(Xt + (obase + p + i)*8) = o;
    }
  }

  #pragma unroll
  for (int off = 32; off; off >>= 1)
    #pragma unroll
    for (int ci = 0; ci < 8; ++ci) s[ci] += __shfl_down(s[ci], off);
  if (lane == 0)
    #pragma unroll
    for (int ci = 0; ci < 8; ++ci) red[wid][ci] = s[ci];
  __syncthreads();
  if (t < 8)
    partial[(size_t)bm*512 + cb*8 + t] = red[0][t] + red[1][t] + red[2][t] + red[3][t];
}

// ---------------- gate: pooled -> MLP + softmax (torch reshape quirk) -----
__global__ __launch_bounds__(256) void gate_kernel(
    const float* __restrict__ partial, const float* __restrict__ Wg1,
    const float* __restrict__ bg1, const float* __restrict__ Wg2,
    const float* __restrict__ bg2, float* __restrict__ wgt)
{
  __shared__ float pl[512*4];   // [c][m]
  __shared__ float g1[128*4];   // [o][m]
  __shared__ float g2[16];      // [e][m]
  const int b = blockIdx.x, tid = threadIdx.x;
  for (int i = tid; i < 2048; i += 256) {
    int c = i >> 2, mm = i & 3;
    pl[c*4 + mm] = partial[(size_t)(b*4 + mm)*512 + c] * (1.0f/4096.0f);
  }
  __syncthreads();
  #pragma unroll
  for (int u = 0; u < 2; ++u) {
    int idx = u*256 + tid;
    int o = idx >> 2, mm = idx & 3;
    float acc = bg1[o];
    for (int c = 0; c < 512; ++c) acc += Wg1[o*512 + c] * pl[c*4 + mm];
    g1[o*4 + mm] = fmaxf(acc, 0.f);
  }
  __syncthreads();
  if (tid < 16) {
    int e = tid >> 2, mm = tid & 3;
    float acc = bg2[e];
    for (int o = 0; o < 128; ++o) acc += Wg2[e*128 + o] * g1[o*4 + mm];
    g2[e*4 + mm] = acc;
  }
  __syncthreads();
  if (tid < 4) {
    int mrow = tid;
    float v0 = g2[mrow*4+0], v1 = g2[mrow*4+1], v2 = g2[mrow*4+2], v3 = g2[mrow*4+3];
    float mx = fmaxf(fmaxf(v0,v1), fmaxf(v2,v3));
    float e0 = expf(v0-mx), e1 = expf(v1-mx), e2 = expf(v2-mx), e3 = expf(v3-mx);
    float inv = 1.0f / (e0+e1+e2+e3);
    wgt[b*16 + mrow*4 + 0] = e0*inv;
    wgt[b*16 + mrow*4 + 1] = e1*inv;
    wgt[b*16 + mrow*4 + 2] = e2*inv;
    wgt[b*16 + mrow*4 + 3] = e3*inv;
  }
}

// ---------------- moe: persistent, dbuf-prefetched tiles, combine fused ----
// 256 blocks x 1024 thr (16 waves), 160 KiB LDS, 1 block/CU, 16 tiles/block.
// LDS: X0 64K | X1 64K | H2 32K.  H1 overlays the just-consumed X buffer.
// Wave (eh = w>>3, o0 = (w&7)*16): acc[2e][4pt] = 32 VGPR.
// Phase A barrier-free (X fully resident, linear [kb][p][ci] layout).
__global__ __launch_bounds__(1024, 4) void moe_kernel(
    const f16* __restrict__ Xt,
    const f16* __restrict__ W1s, const f16* __restrict__ W2s, const f16* __restrict__ W3s,
    const float* __restrict__ b1, const float* __restrict__ b2, const float* __restrict__ b3,
    const float* __restrict__ wgt, float* __restrict__ out)
{
  extern __shared__ __align__(16) char smem[];     // 163840 B
  char* H2 = smem + 131072;

  const int tid  = threadIdx.x;
  const int wave = tid >> 6, lane = tid & 63;
  const int g = lane >> 4, r = lane & 15;
  const int eh = wave >> 3;
  const int o0 = (wave & 7) * 16;

  // zero H2's K-pad (hb 6,7 for each e) once; never overwritten
  if (tid < 512) {
    int e = tid >> 7, off = tid & 127;
    *(uint4*)(H2 + e*8192 + 6144 + off*16) = make_uint4(0u,0u,0u,0u);
  }

  const int bmt0 = blockIdx.x * 16;
  // prologue: stage tile bmt0 -> X0
  {
    const uint4* src = (const uint4*)(Xt + (size_t)bmt0 * 32768);
    #pragma unroll
    for (int j = 0; j < 4; ++j)
      *(uint4*)(smem + tid*16 + j*16384) = src[tid + j*1024];
  }
  int cur = 0;

  #pragma unroll 1
  for (int it = 0; it < 16; ++it) {
    const int bmt  = bmt0 + it;
    const int tile = bmt & 63, m = (bmt >> 6) & 3, b = bmt >> 8;
    char* Xcur = smem + cur*65536;
    char* Xoth = smem + (cur^1)*65536;

    // issue next tile's loads early (land after Phase B)
    uint4 pf0, pf1, pf2, pf3;
    if (it < 15) {
      const uint4* src = (const uint4*)(Xt + (size_t)(bmt+1) * 32768);
      pf0 = src[tid]; pf1 = src[tid+1024]; pf2 = src[tid+2048]; pf3 = src[tid+3072];
    }
    __syncthreads();                     // Xcur fully staged; H1 region free

    // ---- Phase A: L1 for 2 experts, o-strip 16, all 64 p; barrier-free
    f32x4 acc[2][4];
    #pragma unroll
    for (int i = 0; i < 2; ++i)
      #pragma unroll
      for (int pt = 0; pt < 4; ++pt) acc[i][pt] = (f32x4){0.f,0.f,0.f,0.f};

    #pragma unroll
    for (int ks = 0; ks < 16; ++ks) {
      const int kb = ks*4 + g;           // 0..63
      f16x8 bf[4];
      #pragma unroll
      for (int pt = 0; pt < 4; ++pt)
        bf[pt] = *(const f16x8*)(Xcur + (kb*64 + pt*16 + r)*16);
      #pragma unroll
      for (int i = 0; i < 2; ++i) {
        const int e = eh*2 + i;
        f16x8 a = *(const f16x8*)(W1s + ((size_t)((e*64 + kb)*128) + o0 + r)*8);
        acc[i][0] = MFMA16(a, bf[0], acc[i][0]);
        acc[i][1] = MFMA16(a, bf[1], acc[i][1]);
        acc[i][2] = MFMA16(a, bf[2], acc[i][2]);
        acc[i][3] = MFMA16(a, bf[3], acc[i][3]);
      }
    }
    __syncthreads();                     // X consumed -> reuse as H1

    // ---- H1 = relu(acc+b1) -> Xcur as [e][ob16][p64][ci8]
    #pragma unroll
    for (int i = 0; i < 2; ++i) {
      const int e = eh*2 + i;
      const f32x4 bias = *(const f32x4*)(b1 + e*128 + o0 + g*4);
      const int ob = (o0 >> 3) + (g >> 1);
      #pragma unroll
      for (int pt = 0; pt < 4; ++pt) {
        const int p = pt*16 + r;
        f16x4 hv;
        #pragma unroll
        for (int j = 0; j < 4; ++j) hv[j] = (f16)fmaxf(acc[i][pt][j] + bias[j], 0.f);
        *(f16x4*)(Xcur + e*16384 + (ob*64 + p)*16 + (g&1)*8) = hv;
      }
    }
    __syncthreads();

    // ---- L2: 48 fragments (4e x 3ot x 4pt), 3 per wave -> H2 [e][hb8][p][ci]
    #pragma unroll
    for (int s = 0; s < 3; ++s) {
      const int f  = wave*3 + s;
      const int e  = f / 12, ot = (f % 12) >> 2, pt = f & 3;
      const int p  = pt*16 + r;
      f32x4 a2 = {0.f,0.f,0.f,0.f};
      #pragma unroll
      for (int ks = 0; ks < 4; ++ks) {
        const int kb = ks*4 + g;
        f16x8 a  = *(const f16x8*)(W2s + (size_t)((e*16 + kb)*48 + ot*16 + r)*8);
        f16x8 bf = *(const f16x8*)(Xcur + e*16384 + (kb*64 + p)*16);
        a2 = MFMA16(a, bf, a2);
      }
      const f32x4 bias = *(const f32x4*)(b2 + e*48 + ot*16 + g*4);
      const int hb = ot*2 + (g >> 1);
      f16x4 hv;
      #pragma unroll
      for (int j = 0; j < 4; ++j) hv[j] = (f16)fmaxf(a2[j] + bias[j], 0.f);
      *(f16x4*)(H2 + e*8192 + (hb*64 + p)*16 + (g&1)*8) = hv;
    }
    __syncthreads();

    // ---- L3 + weighted combine -> out (waves 0-3, pt = wave)
    if (wave < 4) {
      const int pt = wave, p = pt*16 + r;
      f32x4 sacc = {0.f,0.f,0.f,0.f};
      #pragma unroll
      for (int e = 0; e < 4; ++e) {
        f32x4 a3 = {0.f,0.f,0.f,0.f};
        #pragma unroll
        for (int ks = 0; ks < 2; ++ks) {
          const int kb = ks*4 + g;
          f16x8 a  = *(const f16x8*)(W3s + (size_t)((e*8 + kb)*16 + r)*8);
          f16x8 bf = *(const f16x8*)(H2 + e*8192 + (kb*64 + p)*16);
          a3 = MFMA16(a, bf, a3);
        }
        const float we = wgt[(b*4 + m)*4 + e];
        const f32x4 bv = *(const f32x4*)(b3 + e*16 + g*4);
        #pragma unroll
        for (int j = 0; j < 4; ++j) sacc[j] += we * (a3[j] + bv[j]);
      }
      #pragma unroll
      for (int j = 0; j < 4; ++j) {
        const int o = g*4 + j;
        out[(((size_t)b*16 + o)*4 + m)*4096 + (size_t)tile*64 + p] = sacc[j];
      }
    }

    // ---- write prefetched tile into the other buffer (guarded by next top barrier)
    if (it < 15) {
      *(uint4*)(Xoth + tid*16)         = pf0;
      *(uint4*)(Xoth + tid*16 + 16384) = pf1;
      *(uint4*)(Xoth + tid*16 + 32768) = pf2;
      *(uint4*)(Xoth + tid*16 + 49152) = pf3;
    }
    cur ^= 1;
  }
}

// ---------------- launcher ----------------
extern "C" void kernel_launch(void* const* d_in, const int* in_sizes, int n_in,
                              void* d_out, int out_size, void* d_ws, size_t ws_size,
                              hipStream_t stream) {
  const float* x   = (const float*)d_in[0];
  const float* W1  = (const float*)d_in[1];
  const float* b1  = (const float*)d_in[2];
  const float* W2  = (const float*)d_in[3];
  const float* b2  = (const float*)d_in[4];
  const float* W3  = (const float*)d_in[5];
  const float* b3  = (const float*)d_in[6];
  const float* Wg1 = (const float*)d_in[7];
  const float* bg1 = (const float*)d_in[8];
  const float* Wg2 = (const float*)d_in[9];
  const float* bg2 = (const float*)d_in[10];
  float* out = (float*)d_out;

  char* ws = (char*)d_ws;
  float* wgt     = (float*)ws;                         //      1 KiB [b][m][e]
  f16*   W1s     = (f16*)(ws + 4096);                  //    512 KiB
  f16*   W2s     = (f16*)(ws + 4096 + 524288);         //     48 KiB
  f16*   W3s     = (f16*)(ws + 4096 + 524288 + 49152); //      8 KiB
  float* partial = (float*)(ws + (1u<<20));            //    128 KiB [bm][c]
  f16*   Xt      = (f16*)(ws + (16u<<20));             //    256 MiB [bmt][kb][p][ci]

  hipFuncSetAttribute(reinterpret_cast<const void*>(moe_kernel),
                      hipFuncAttributeMaxDynamicSharedMemorySize, 163840);

  prep_kernel<<<(262144 + 24576 + 4096 + 255)/256, 256, 0, stream>>>(W1, W2, W3, W1s, W2s, W3s);
  xprep_kernel<<<64*64, 256, 0, stream>>>(x, Xt, partial);
  gate_kernel<<<BDIM, 256, 0, stream>>>(partial, Wg1, bg1, Wg2, bg2, wgt);
  moe_kernel<<<256, 1024, 163840, stream>>>(Xt, W1s, W2s, W3s, b1, b2, b3, wgt, out);
}